// Round 4
// baseline (809.744 us; speedup 1.0000x reference)
//
#include <hip/hip_runtime.h>
#include <hip/hip_bf16.h>

// LSTM cell: z = [x|h] @ Wstack^T + b ; gates -> c_t, h_t.
// M=4096, K=4096, N=2048 per gate x 4 gates. bf16 MFMA GEMM.
// R1: XOR bank-swizzle -> SQ_LDS_BANK_CONFLICT = 0. KEEP.
// R2: BK64 = NEUTRAL -> kernel is LDS-READ-BW bound, not barrier-count bound.
// R3: raise FLOP/LDS-byte 2.7x: 32x32x16 MFMA (2x FLOP per fragment byte)
//     + wave tile 64m x 32h x 4gates (2 A-frags + 4 B-frags -> 8 MFMA).
//     BM=256, BN=32, BK=32, LDS 24KB. Swizzle: 16B slot = chunk ^ (row&3).

#define M_DIM 4096
#define K_DIM 4096
#define H_DIM 2048
#define BM 256
#define BN 32
#define BK 32

typedef __attribute__((ext_vector_type(8))) short bf16x8;
typedef __attribute__((ext_vector_type(8))) unsigned short u16x8;
typedef __attribute__((ext_vector_type(16))) float f32x16;

__device__ __forceinline__ unsigned short f2bf(float f) {
    union { float f; unsigned int u; } v; v.f = f;
    unsigned int u = v.u;
    unsigned int r = u + 0x7FFFu + ((u >> 16) & 1u);   // round-to-nearest-even
    return (unsigned short)(r >> 16);
}

__device__ __forceinline__ float sigmoid_f(float x) {
    return 1.0f / (1.0f + __expf(-x));
}
__device__ __forceinline__ float tanh_f(float x) {
    return 2.0f / (1.0f + __expf(-2.0f * x)) - 1.0f;
}

__device__ __forceinline__ void async_load16(const unsigned short* g, unsigned short* l) {
    __builtin_amdgcn_global_load_lds(
        (const __attribute__((address_space(1))) void*)g,
        (__attribute__((address_space(3))) void*)l,
        16, 0, 0);
}

// ---------------- fp32 -> bf16 conversion prepass ----------------
// xh_bf: [4096][4096] = [x_t | h_t_1]; w_bf: [8192][4096] = Wi,Wf,Wo,Wc stacked.
__global__ __launch_bounds__(256) void convert_all(
        const float* __restrict__ x, const float* __restrict__ h,
        const float* __restrict__ Wi, const float* __restrict__ Wf,
        const float* __restrict__ Wo, const float* __restrict__ Wc,
        u16x8* __restrict__ xh_bf, u16x8* __restrict__ w_bf) {
    const int XHT = (M_DIM * K_DIM) / 8;          // 2,097,152
    int t = blockIdx.x * 256 + threadIdx.x;       // 0 .. 6,291,455
    const float* src;
    u16x8* dst;
    if (t < XHT) {
        int e = t * 8;
        int row = e >> 12;
        int col = e & 4095;
        src = (col < 2048) ? &x[(size_t)row * 2048 + col]
                           : &h[(size_t)row * 2048 + (col - 2048)];
        dst = xh_bf + t;
    } else {
        int g2 = t - XHT;                         // 0 .. 4,194,303
        long e = (long)g2 * 8;
        int row = (int)(e >> 12);                 // 0..8191
        int col = (int)(e & 4095);
        int gate = row >> 11;
        const float* Ws = (gate == 0) ? Wi : (gate == 1) ? Wf : (gate == 2) ? Wo : Wc;
        src = &Ws[(size_t)(row & 2047) * 4096 + col];
        dst = w_bf + g2;
    }
    float4 v0 = *(const float4*)src;
    float4 v1 = *(const float4*)(src + 4);
    u16x8 o;
    o[0] = f2bf(v0.x); o[1] = f2bf(v0.y); o[2] = f2bf(v0.z); o[3] = f2bf(v0.w);
    o[4] = f2bf(v1.x); o[5] = f2bf(v1.y); o[6] = f2bf(v1.z); o[7] = f2bf(v1.w);
    *dst = o;
}

// ---------------- fused LSTM GEMM ----------------
// grid (H/BN=64, M/BM=16), block 256 (4 waves). Wave w: m in [64w, 64w+64),
// h-cols [0,32) of the block's n-tile, all 4 gates (epilogue wave-local).
// MFMA 32x32x16: A[m=lane&31][k=(lane>>5)*8+j], B likewise (K-major rows);
// C/D: col=lane&31, row=(reg&3)+8*(reg>>2)+4*(lane>>5)  [m74/m101 verified].
template <bool DMA>
__global__ __launch_bounds__(256) void lstm_gemm(
    const unsigned short* __restrict__ xh_bf, const unsigned short* __restrict__ w_bf,
    const float* __restrict__ x_t, const float* __restrict__ h_t_1,
    const float* __restrict__ Wi, const float* __restrict__ Wf,
    const float* __restrict__ Wo, const float* __restrict__ Wc,
    const float* __restrict__ b_i, const float* __restrict__ b_f,
    const float* __restrict__ b_o, const float* __restrict__ b_c,
    const float* __restrict__ c_prev,
    float* __restrict__ h_out, float* __restrict__ c_out) {

    __shared__ __align__(16) unsigned short sA[BM * BK];      // [256][32] 16KB
    __shared__ __align__(16) unsigned short sB[4 * BN * BK];  // [4][32][32] 8KB

    const int tid  = threadIdx.x;
    const int w    = tid >> 6;
    const int lane = tid & 63;
    const int l32  = lane & 31;
    const int half = lane >> 5;

    const int mBase = blockIdx.y * BM;
    const int nBase = blockIdx.x * BN;

    f32x16 acc[4][2] = {};   // [gate][mt] -- 128 AGPRs

    for (int k0 = 0; k0 < K_DIM; k0 += BK) {
        __syncthreads();   // protect LDS while prior step's reads retire
        if constexpr (DMA) {
#pragma unroll
            for (int r = 0; r < 4; ++r) {           // A: 1024 chunks of 16B
                int cc  = r * 256 + tid;
                int row = cc >> 2;
                int lc  = (cc & 3) ^ (row & 3);     // logical chunk for this slot
                async_load16(xh_bf + (size_t)(mBase + row) * K_DIM + k0 + lc * 8,
                             &sA[cc * 8]);
            }
#pragma unroll
            for (int r = 0; r < 2; ++r) {           // B: 512 chunks (4 gates x 32 rows x 4)
                int cc   = r * 256 + tid;
                int gate = cc >> 7;
                int row  = (cc >> 2) & 31;
                int lc   = (cc & 3) ^ (row & 3);
                async_load16(w_bf + (size_t)(gate * H_DIM + nBase + row) * K_DIM + k0 + lc * 8,
                             &sB[cc * 8]);
            }
        } else {
            const float* Asrc = (k0 < 2048) ? x_t : h_t_1;
            int kloc = k0 & 2047;
#pragma unroll
            for (int r = 0; r < 8; ++r) {           // A: 2048 float4 chunks
                int cc  = r * 256 + tid;
                int row = cc >> 3;
                int ko  = (cc & 7) * 4;             // short offset 0..28
                float4 v = *(const float4*)&Asrc[(size_t)(mBase + row) * 2048 + kloc + ko];
                *(ushort4*)&sA[row * BK + (((ko >> 3) ^ (row & 3)) * 8) + (ko & 7)] =
                    make_ushort4(f2bf(v.x), f2bf(v.y), f2bf(v.z), f2bf(v.w));
            }
            const float* Wg[4] = {Wi, Wf, Wo, Wc};
#pragma unroll
            for (int r = 0; r < 4; ++r) {           // B: 1024 float4 chunks
                int cc   = r * 256 + tid;
                int gate = cc >> 8;
                int row  = (cc >> 3) & 31;
                int ko   = (cc & 7) * 4;
                float4 v = *(const float4*)&Wg[gate][(size_t)(nBase + row) * K_DIM + k0 + ko];
                *(ushort4*)&sB[gate * (BN * BK) + row * BK +
                               (((ko >> 3) ^ (row & 3)) * 8) + (ko & 7)] =
                    make_ushort4(f2bf(v.x), f2bf(v.y), f2bf(v.z), f2bf(v.w));
            }
        }
        __syncthreads();   // drains vmcnt for global_load_lds too

#pragma unroll
        for (int hk = 0; hk < 2; ++hk) {
            int lc = hk * 2 + half;                 // logical 16B chunk (k = lc*8)
            bf16x8 av[2];
#pragma unroll
            for (int mt = 0; mt < 2; ++mt) {
                int row = w * 64 + mt * 32 + l32;
                av[mt] = *(const bf16x8*)&sA[row * BK + ((lc ^ (row & 3)) * 8)];
            }
            bf16x8 bv[4];
#pragma unroll
            for (int g = 0; g < 4; ++g) {
                int row = l32;
                bv[g] = *(const bf16x8*)&sB[g * (BN * BK) + row * BK + ((lc ^ (row & 3)) * 8)];
            }
#pragma unroll
            for (int g = 0; g < 4; ++g)
#pragma unroll
                for (int mt = 0; mt < 2; ++mt)
                    acc[g][mt] = __builtin_amdgcn_mfma_f32_32x32x16_bf16(
                        av[mt], bv[g], acc[g][mt], 0, 0, 0);
        }
    }

    // Epilogue: wave-local gates -> c_t, h_t.
    // acc[g][mt] reg j: n = nBase + l32, m = mBase + w*64 + mt*32 + (j&3)+8*(j>>2)+4*half.
    {
        int n = nBase + l32;
        float bi = b_i[n], bf = b_f[n], bo = b_o[n], bc = b_c[n];
#pragma unroll
        for (int mt = 0; mt < 2; ++mt) {
#pragma unroll
            for (int j = 0; j < 16; ++j) {
                int m = mBase + w * 64 + mt * 32 + (j & 3) + 8 * (j >> 2) + 4 * half;
                float zi = acc[0][mt][j] + bi;
                float zf = acc[1][mt][j] + bf;
                float zo = acc[2][mt][j] + bo;
                float zc = acc[3][mt][j] + bc;
                float ig = sigmoid_f(zi);
                float fg = sigmoid_f(zf);
                float og = sigmoid_f(zo);
                float ch = tanh_f(zc);
                size_t idx = (size_t)m * H_DIM + n;
                float c = fg * c_prev[idx] + ig * ch;
                c_out[idx] = c;
                h_out[idx] = og * tanh_f(c);
            }
        }
    }
}

extern "C" void kernel_launch(void* const* d_in, const int* in_sizes, int n_in,
                              void* d_out, int out_size, void* d_ws, size_t ws_size,
                              hipStream_t stream) {
    const float* x_t   = (const float*)d_in[0];
    const float* h_t_1 = (const float*)d_in[1];
    const float* c_t_1 = (const float*)d_in[2];
    const float* W_i   = (const float*)d_in[3];
    const float* b_i   = (const float*)d_in[4];
    const float* W_f   = (const float*)d_in[5];
    const float* b_f   = (const float*)d_in[6];
    const float* W_o   = (const float*)d_in[7];
    const float* b_o   = (const float*)d_in[8];
    const float* W_c   = (const float*)d_in[9];
    const float* b_c   = (const float*)d_in[10];

    float* h_out = (float*)d_out;
    float* c_out = h_out + (size_t)M_DIM * H_DIM;

    dim3 grid(H_DIM / BN, M_DIM / BM);   // (64, 16)

    const size_t need = (size_t)M_DIM * K_DIM * 2 + (size_t)4 * H_DIM * K_DIM * 2; // 96 MB
    if (ws_size >= need) {
        unsigned short* xh_bf = (unsigned short*)d_ws;
        unsigned short* w_bf  = xh_bf + (size_t)M_DIM * K_DIM;
        int total_threads = (M_DIM * K_DIM + 4 * H_DIM * K_DIM) / 8;  // 6,291,456
        convert_all<<<total_threads / 256, 256, 0, stream>>>(
            x_t, h_t_1, W_i, W_f, W_o, W_c, (u16x8*)xh_bf, (u16x8*)w_bf);
        lstm_gemm<true><<<grid, 256, 0, stream>>>(
            xh_bf, w_bf, nullptr, nullptr, nullptr, nullptr, nullptr, nullptr,
            b_i, b_f, b_o, b_c, c_t_1, h_out, c_out);
    } else {
        lstm_gemm<false><<<grid, 256, 0, stream>>>(
            nullptr, nullptr, x_t, h_t_1, W_i, W_f, W_o, W_c,
            b_i, b_f, b_o, b_c, c_t_1, h_out, c_out);
    }
}

// Round 5
// 543.246 us; speedup vs baseline: 1.4906x; 1.4906x over previous
//
#include <hip/hip_runtime.h>
#include <hip/hip_bf16.h>

// LSTM cell: z = [x|h] @ Wstack^T + b ; gates -> c_t, h_t.
// M=4096, K=4096, N=2048 per gate x 4 gates. bf16 MFMA GEMM.
// R1: XOR bank-swizzle (64B rows) -> 0 conflicts at 16x16 pattern. KEEP idea.
// R2: BK64, 16x16x32, wave=32m x 32h x 4g: 413us, MfmaUtil 29, conflicts 0.
// R3: 32x32x16 + 128 AGPR acc = FAILED (1 wave/SIMD, swizzle broke at 64B rows
//     with 32-row reads -> 7.5e7 conflicts). REVERTED.
// R4: R2 structure + 2x2 wave partition: wave = 64m x 16h x 4g.
//     Reads 8 b128 per 16 MFMA (was 10), acc stays 64 AGPR, sw64 swizzle
//     (128B rows, slot = chunk ^ (row&7)) identical read pattern to R2 -> 0
//     conflicts. __launch_bounds__(256,3) targets 3 waves/SIMD.

#define M_DIM 4096
#define K_DIM 4096
#define H_DIM 2048
#define BM 128
#define BH 32          // h-cols per block (per gate); n_total per block = 128
#define BK 64

typedef __attribute__((ext_vector_type(8))) short bf16x8;
typedef __attribute__((ext_vector_type(8))) unsigned short u16x8;
typedef __attribute__((ext_vector_type(4))) float f32x4;

__device__ __forceinline__ unsigned short f2bf(float f) {
    union { float f; unsigned int u; } v; v.f = f;
    unsigned int u = v.u;
    unsigned int r = u + 0x7FFFu + ((u >> 16) & 1u);   // round-to-nearest-even
    return (unsigned short)(r >> 16);
}

__device__ __forceinline__ float sigmoid_f(float x) {
    return 1.0f / (1.0f + __expf(-x));
}
__device__ __forceinline__ float tanh_f(float x) {
    return 2.0f / (1.0f + __expf(-2.0f * x)) - 1.0f;
}

// [rows][64] shorts: 16B chunk c of row r stored at slot (c ^ (r&7)).
// Row = 128B = all 32 banks; 8-slot XOR spreads any 16-row x fixed-chunk
// read over all 8 four-bank groups (2 lanes/bank = free). R2-verified: 0.
__device__ __forceinline__ int sw64(int row, int koff) {
    int c  = koff >> 3;
    int sc = c ^ (row & 7);
    return row * BK + sc * 8 + (koff & 7);
}

__device__ __forceinline__ void async_load16(const unsigned short* g, unsigned short* l) {
    __builtin_amdgcn_global_load_lds(
        (const __attribute__((address_space(1))) void*)g,
        (__attribute__((address_space(3))) void*)l,
        16, 0, 0);
}

// ---------------- fp32 -> bf16 conversion prepass ----------------
// xh_bf: [4096][4096] = [x_t | h_t_1]; w_bf: [8192][4096] = Wi,Wf,Wo,Wc stacked.
__global__ __launch_bounds__(256) void convert_all(
        const float* __restrict__ x, const float* __restrict__ h,
        const float* __restrict__ Wi, const float* __restrict__ Wf,
        const float* __restrict__ Wo, const float* __restrict__ Wc,
        u16x8* __restrict__ xh_bf, u16x8* __restrict__ w_bf) {
    const int XHT = (M_DIM * K_DIM) / 8;          // 2,097,152
    int t = blockIdx.x * 256 + threadIdx.x;       // 0 .. 6,291,455
    const float* src;
    u16x8* dst;
    if (t < XHT) {
        int e = t * 8;
        int row = e >> 12;
        int col = e & 4095;
        src = (col < 2048) ? &x[(size_t)row * 2048 + col]
                           : &h[(size_t)row * 2048 + (col - 2048)];
        dst = xh_bf + t;
    } else {
        int g2 = t - XHT;                         // 0 .. 4,194,303
        long e = (long)g2 * 8;
        int row = (int)(e >> 12);                 // 0..8191
        int col = (int)(e & 4095);
        int gate = row >> 11;
        const float* Ws = (gate == 0) ? Wi : (gate == 1) ? Wf : (gate == 2) ? Wo : Wc;
        src = &Ws[(size_t)(row & 2047) * 4096 + col];
        dst = w_bf + g2;
    }
    float4 v0 = *(const float4*)src;
    float4 v1 = *(const float4*)(src + 4);
    u16x8 o;
    o[0] = f2bf(v0.x); o[1] = f2bf(v0.y); o[2] = f2bf(v0.z); o[3] = f2bf(v0.w);
    o[4] = f2bf(v1.x); o[5] = f2bf(v1.y); o[6] = f2bf(v1.z); o[7] = f2bf(v1.w);
    *dst = o;
}

// ---------------- fused LSTM GEMM ----------------
// grid (H/BH=64, M/BM=32), block 256 = 4 waves in 2x2:
//   wm = w&1 -> m-half [64 rows], wh = w>>1 -> h-half [16 cols].
// Wave: 64m x 16h x 4 gates; per K32: 4 A-frags + 4 B-frags -> 16 MFMA.
template <bool DMA>
__global__ __launch_bounds__(256, 3) void lstm_gemm(
    const unsigned short* __restrict__ xh_bf, const unsigned short* __restrict__ w_bf,
    const float* __restrict__ x_t, const float* __restrict__ h_t_1,
    const float* __restrict__ Wi, const float* __restrict__ Wf,
    const float* __restrict__ Wo, const float* __restrict__ Wc,
    const float* __restrict__ b_i, const float* __restrict__ b_f,
    const float* __restrict__ b_o, const float* __restrict__ b_c,
    const float* __restrict__ c_prev,
    float* __restrict__ h_out, float* __restrict__ c_out) {

    __shared__ __align__(16) unsigned short sA[BM * BK];      // [128][64] 16KB
    __shared__ __align__(16) unsigned short sB[4 * BH * BK];  // [4][32][64] 16KB

    const int tid  = threadIdx.x;
    const int w    = tid >> 6;
    const int lane = tid & 63;
    const int l16  = lane & 15;
    const int quad = lane >> 4;
    const int wm   = w & 1;
    const int wh   = w >> 1;

    const int mBase = blockIdx.y * BM;
    const int nBase = blockIdx.x * BH;

    f32x4 acc[4][4] = {};   // [gate][mt] -- 64 AGPRs

    // Loop-invariant pieces of frag addresses.
    int arow[4], ar7[4];
#pragma unroll
    for (int mt = 0; mt < 4; ++mt) {
        arow[mt] = (wm * 64 + mt * 16 + l16) * BK;
        ar7[mt]  = (wm * 64 + mt * 16 + l16) & 7;
    }
    const int brow = (wh * 16 + l16);
    const int brow_off = brow * BK;
    const int br7 = brow & 7;

    // DMA source pointers (advance by BK per step).
    const unsigned short* aSrc = nullptr;
    const unsigned short* bSrc = nullptr;
    int aDst = 0, bDst = 0;
    if constexpr (DMA) {
        int cc = tid;                       // A: rows 0..31 (r adds 32 rows)
        int arowi = cc >> 3;
        // per-r row offset is +32 rows; (row&7) invariant under +32.
        int alc = (cc & 7) ^ (arowi & 7);
        aSrc = xh_bf + (size_t)(mBase + arowi) * K_DIM + alc * 8;
        aDst = cc * 8;
        int gate = cc >> 8;                 // 0 for tid<256: B uses r-loop gates
        (void)gate;
        int browi = (cc >> 3) & 31;
        int blc = (cc & 7) ^ (browi & 7);
        bSrc = w_bf + (size_t)(nBase + browi) * K_DIM + blc * 8;  // gate 0 base
        bDst = cc * 8;
    }

    for (int k0 = 0; k0 < K_DIM; k0 += BK) {
        __syncthreads();   // protect LDS while prior step's reads retire
        if constexpr (DMA) {
#pragma unroll
            for (int r = 0; r < 4; ++r)     // A: 128 rows x 8 chunks, 32 rows per r
                async_load16(aSrc + k0 + (size_t)r * 32 * K_DIM, &sA[aDst + r * 2048]);
#pragma unroll
            for (int r = 0; r < 4; ++r)     // B: gate r (32 rows x 8 chunks each)
                async_load16(bSrc + k0 + (size_t)r * H_DIM * K_DIM, &sB[bDst + r * 2048]);
        } else {
            const float* Asrc = (k0 < 2048) ? x_t : h_t_1;
            int kloc = k0 & 2047;
#pragma unroll
            for (int r = 0; r < 8; ++r) {   // A: 2048 float4 chunks
                int cc  = r * 256 + tid;
                int row = cc >> 4;
                int ko  = (cc & 15) * 4;
                float4 v = *(const float4*)&Asrc[(size_t)(mBase + row) * 2048 + kloc + ko];
                *(ushort4*)&sA[sw64(row, ko)] =
                    make_ushort4(f2bf(v.x), f2bf(v.y), f2bf(v.z), f2bf(v.w));
            }
            const float* Wg[4] = {Wi, Wf, Wo, Wc};
#pragma unroll
            for (int r = 0; r < 8; ++r) {   // B: 2048 float4 chunks
                int cc   = r * 256 + tid;
                int gate = cc >> 9;
                int row  = (cc >> 4) & 31;
                int ko   = (cc & 15) * 4;
                float4 v = *(const float4*)&Wg[gate][(size_t)(nBase + row) * K_DIM + k0 + ko];
                *(ushort4*)&sB[gate * (BH * BK) + sw64(row, ko)] =
                    make_ushort4(f2bf(v.x), f2bf(v.y), f2bf(v.z), f2bf(v.w));
            }
        }
        __syncthreads();   // drains vmcnt for global_load_lds too

#pragma unroll
        for (int hk = 0; hk < 2; ++hk) {
            const int c = hk * 4 + quad;            // logical chunk, k = c*8
            bf16x8 av[4];
#pragma unroll
            for (int mt = 0; mt < 4; ++mt)
                av[mt] = *(const bf16x8*)&sA[arow[mt] + ((c ^ ar7[mt]) << 3)];
            bf16x8 bv[4];
#pragma unroll
            for (int g = 0; g < 4; ++g)
                bv[g] = *(const bf16x8*)&sB[g * (BH * BK) + brow_off + ((c ^ br7) << 3)];
#pragma unroll
            for (int g = 0; g < 4; ++g)
#pragma unroll
                for (int mt = 0; mt < 4; ++mt)
                    acc[g][mt] = __builtin_amdgcn_mfma_f32_16x16x32_bf16(
                        av[mt], bv[g], acc[g][mt], 0, 0, 0);
        }
    }

    // Epilogue: wave-local. C/D: col=lane&15 -> n, row=quad*4+i -> m-within-16.
    {
        int n = nBase + wh * 16 + l16;
        float bi = b_i[n], bf = b_f[n], bo = b_o[n], bc = b_c[n];
#pragma unroll
        for (int mt = 0; mt < 4; ++mt) {
#pragma unroll
            for (int i = 0; i < 4; ++i) {
                int m = mBase + wm * 64 + mt * 16 + quad * 4 + i;
                float zi = acc[0][mt][i] + bi;
                float zf = acc[1][mt][i] + bf;
                float zo = acc[2][mt][i] + bo;
                float zc = acc[3][mt][i] + bc;
                float ig = sigmoid_f(zi);
                float fg = sigmoid_f(zf);
                float og = sigmoid_f(zo);
                float ch = tanh_f(zc);
                size_t idx = (size_t)m * H_DIM + n;
                float c = fg * c_prev[idx] + ig * ch;
                c_out[idx] = c;
                h_out[idx] = og * tanh_f(c);
            }
        }
    }
}

extern "C" void kernel_launch(void* const* d_in, const int* in_sizes, int n_in,
                              void* d_out, int out_size, void* d_ws, size_t ws_size,
                              hipStream_t stream) {
    const float* x_t   = (const float*)d_in[0];
    const float* h_t_1 = (const float*)d_in[1];
    const float* c_t_1 = (const float*)d_in[2];
    const float* W_i   = (const float*)d_in[3];
    const float* b_i   = (const float*)d_in[4];
    const float* W_f   = (const float*)d_in[5];
    const float* b_f   = (const float*)d_in[6];
    const float* W_o   = (const float*)d_in[7];
    const float* b_o   = (const float*)d_in[8];
    const float* W_c   = (const float*)d_in[9];
    const float* b_c   = (const float*)d_in[10];

    float* h_out = (float*)d_out;
    float* c_out = h_out + (size_t)M_DIM * H_DIM;

    dim3 grid(H_DIM / BH, M_DIM / BM);   // (64, 32)

    const size_t need = (size_t)M_DIM * K_DIM * 2 + (size_t)4 * H_DIM * K_DIM * 2; // 96 MB
    if (ws_size >= need) {
        unsigned short* xh_bf = (unsigned short*)d_ws;
        unsigned short* w_bf  = xh_bf + (size_t)M_DIM * K_DIM;
        int total_threads = (M_DIM * K_DIM + 4 * H_DIM * K_DIM) / 8;  // 6,291,456
        convert_all<<<total_threads / 256, 256, 0, stream>>>(
            x_t, h_t_1, W_i, W_f, W_o, W_c, (u16x8*)xh_bf, (u16x8*)w_bf);
        lstm_gemm<true><<<grid, 256, 0, stream>>>(
            xh_bf, w_bf, nullptr, nullptr, nullptr, nullptr, nullptr, nullptr,
            b_i, b_f, b_o, b_c, c_t_1, h_out, c_out);
    } else {
        lstm_gemm<false><<<grid, 256, 0, stream>>>(
            nullptr, nullptr, x_t, h_t_1, W_i, W_f, W_o, W_c,
            b_i, b_f, b_o, b_c, c_t_1, h_out, c_out);
    }
}

// Round 6
// 524.853 us; speedup vs baseline: 1.5428x; 1.0350x over previous
//
#include <hip/hip_runtime.h>
#include <hip/hip_bf16.h>

// LSTM cell: z = [x|h] @ Wstack^T + b ; gates -> c_t, h_t.
// M=4096, K=4096, N=2048 per gate x 4 gates. bf16 MFMA GEMM.
// R2: BK64, 16x16x32, conflicts 0 (8-slot XOR swizzle on 128B rows). KEEP.
// R3: 32x32x16 / 128 AGPR = occupancy collapse. REVERTED.
// R4: 2x2 wave partition (64m x 16h x 4g per wave): 311us, MfmaUtil 40.6,
//     VGPR 68 + AGPR 64 = 132 regs -> 3 waves/SIMD.
// R5: register diet to cross the 128-reg / 4-waves-per-SIMD boundary:
//     swizzle XOR term (row&7) == l16&7 for ALL fragments (wm*64, mt*16,
//     wh*16 all ==0 mod 8) -> one read offset + immediate strides;
//     __launch_bounds__(256,4). Target VGPR<=64.

#define M_DIM 4096
#define K_DIM 4096
#define H_DIM 2048
#define BM 128
#define BH 32          // h-cols per block (per gate)
#define BK 64

typedef __attribute__((ext_vector_type(8))) short bf16x8;
typedef __attribute__((ext_vector_type(8))) unsigned short u16x8;
typedef __attribute__((ext_vector_type(4))) float f32x4;

__device__ __forceinline__ unsigned short f2bf(float f) {
    union { float f; unsigned int u; } v; v.f = f;
    unsigned int u = v.u;
    unsigned int r = u + 0x7FFFu + ((u >> 16) & 1u);   // round-to-nearest-even
    return (unsigned short)(r >> 16);
}

__device__ __forceinline__ float sigmoid_f(float x) {
    return 1.0f / (1.0f + __expf(-x));
}
__device__ __forceinline__ float tanh_f(float x) {
    return 2.0f / (1.0f + __expf(-2.0f * x)) - 1.0f;
}

// [rows][64] shorts: 16B chunk c of row r stored at slot (c ^ (r&7)).
__device__ __forceinline__ int sw64(int row, int koff) {
    int c  = koff >> 3;
    int sc = c ^ (row & 7);
    return row * BK + sc * 8 + (koff & 7);
}

__device__ __forceinline__ void async_load16(const unsigned short* g, unsigned short* l) {
    __builtin_amdgcn_global_load_lds(
        (const __attribute__((address_space(1))) void*)g,
        (__attribute__((address_space(3))) void*)l,
        16, 0, 0);
}

// ---------------- fp32 -> bf16 conversion prepass ----------------
__global__ __launch_bounds__(256) void convert_all(
        const float* __restrict__ x, const float* __restrict__ h,
        const float* __restrict__ Wi, const float* __restrict__ Wf,
        const float* __restrict__ Wo, const float* __restrict__ Wc,
        u16x8* __restrict__ xh_bf, u16x8* __restrict__ w_bf) {
    const int XHT = (M_DIM * K_DIM) / 8;          // 2,097,152
    int t = blockIdx.x * 256 + threadIdx.x;       // 0 .. 6,291,455
    const float* src;
    u16x8* dst;
    if (t < XHT) {
        int e = t * 8;
        int row = e >> 12;
        int col = e & 4095;
        src = (col < 2048) ? &x[(size_t)row * 2048 + col]
                           : &h[(size_t)row * 2048 + (col - 2048)];
        dst = xh_bf + t;
    } else {
        int g2 = t - XHT;                         // 0 .. 4,194,303
        long e = (long)g2 * 8;
        int row = (int)(e >> 12);                 // 0..8191
        int col = (int)(e & 4095);
        int gate = row >> 11;
        const float* Ws = (gate == 0) ? Wi : (gate == 1) ? Wf : (gate == 2) ? Wo : Wc;
        src = &Ws[(size_t)(row & 2047) * 4096 + col];
        dst = w_bf + g2;
    }
    float4 v0 = *(const float4*)src;
    float4 v1 = *(const float4*)(src + 4);
    u16x8 o;
    o[0] = f2bf(v0.x); o[1] = f2bf(v0.y); o[2] = f2bf(v0.z); o[3] = f2bf(v0.w);
    o[4] = f2bf(v1.x); o[5] = f2bf(v1.y); o[6] = f2bf(v1.z); o[7] = f2bf(v1.w);
    *dst = o;
}

// ---------------- fused LSTM GEMM ----------------
// grid (H/BH=64, M/BM=32), block 256 = 4 waves in 2x2:
//   wm = w&1 -> m-half [64 rows], wh = w>>1 -> h-half [16 cols].
// Wave: 64m x 16h x 4 gates; per K32: 4 A-frags + 4 B-frags -> 16 MFMA.
template <bool DMA>
__global__ __launch_bounds__(256, 4) void lstm_gemm(
    const unsigned short* __restrict__ xh_bf, const unsigned short* __restrict__ w_bf,
    const float* __restrict__ x_t, const float* __restrict__ h_t_1,
    const float* __restrict__ Wi, const float* __restrict__ Wf,
    const float* __restrict__ Wo, const float* __restrict__ Wc,
    const float* __restrict__ b_i, const float* __restrict__ b_f,
    const float* __restrict__ b_o, const float* __restrict__ b_c,
    const float* __restrict__ c_prev,
    float* __restrict__ h_out, float* __restrict__ c_out) {

    __shared__ __align__(16) unsigned short sA[BM * BK];      // [128][64] 16KB
    __shared__ __align__(16) unsigned short sB[4 * BH * BK];  // [4][32][64] 16KB

    const int tid  = threadIdx.x;
    const int w    = tid >> 6;
    const int lane = tid & 63;
    const int l16  = lane & 15;
    const int quad = lane >> 4;
    const int wm   = w & 1;
    const int wh   = w >> 1;
    const int s7   = l16 & 7;          // swizzle XOR term, identical for ALL frags

    const int mBase = blockIdx.y * BM;
    const int nBase = blockIdx.x * BH;

    f32x4 acc[4][4] = {};   // [gate][mt] -- 64 AGPRs

    // Fragment read bases (shorts). Row&7 == s7 for every fragment row.
    const int aBase = (wm * 64 + l16) * BK;    // + mt*16*BK (imm) + chunk-offset
    const int bBase = (wh * 16 + l16) * BK;    // + g*BH*BK (imm)  + chunk-offset

    // DMA source pointers (advance by BK per step).
    const unsigned short* aSrc = nullptr;
    const unsigned short* bSrc = nullptr;
    if constexpr (DMA) {
        int arowi = tid >> 3;                       // 0..31, r adds 32 rows
        int alc   = (tid & 7) ^ (arowi & 7);        // logical chunk for slot tid&7
        aSrc = xh_bf + (size_t)(mBase + arowi) * K_DIM + alc * 8;
        int browi = (tid >> 3) & 31;
        int blc   = (tid & 7) ^ (browi & 7);
        bSrc = w_bf + (size_t)(nBase + browi) * K_DIM + blc * 8;  // gate 0 base
    }
    const int dmaDst = tid * 8;

    for (int k0 = 0; k0 < K_DIM; k0 += BK) {
        __syncthreads();   // protect LDS while prior step's reads retire
        if constexpr (DMA) {
#pragma unroll
            for (int r = 0; r < 4; ++r)     // A: 128 rows x 8 chunks, 32 rows per r
                async_load16(aSrc + (size_t)r * 32 * K_DIM, &sA[dmaDst + r * 2048]);
#pragma unroll
            for (int r = 0; r < 4; ++r)     // B: gate r (32 rows x 8 chunks each)
                async_load16(bSrc + (size_t)r * H_DIM * K_DIM, &sB[dmaDst + r * 2048]);
            aSrc += BK;
            bSrc += BK;
        } else {
            const float* Asrc = (k0 < 2048) ? x_t : h_t_1;
            int kloc = k0 & 2047;
#pragma unroll
            for (int r = 0; r < 8; ++r) {   // A: 2048 float4 chunks
                int cc  = r * 256 + tid;
                int row = cc >> 4;
                int ko  = (cc & 15) * 4;
                float4 v = *(const float4*)&Asrc[(size_t)(mBase + row) * 2048 + kloc + ko];
                *(ushort4*)&sA[sw64(row, ko)] =
                    make_ushort4(f2bf(v.x), f2bf(v.y), f2bf(v.z), f2bf(v.w));
            }
            const float* Wg[4] = {Wi, Wf, Wo, Wc};
#pragma unroll
            for (int r = 0; r < 8; ++r) {   // B: 2048 float4 chunks
                int cc   = r * 256 + tid;
                int gate = cc >> 9;
                int row  = (cc >> 4) & 31;
                int ko   = (cc & 15) * 4;
                float4 v = *(const float4*)&Wg[gate][(size_t)(nBase + row) * K_DIM + k0 + ko];
                *(ushort4*)&sB[gate * (BH * BK) + sw64(row, ko)] =
                    make_ushort4(f2bf(v.x), f2bf(v.y), f2bf(v.z), f2bf(v.w));
            }
        }
        __syncthreads();   // drains vmcnt for global_load_lds too

#pragma unroll
        for (int hk = 0; hk < 2; ++hk) {
            const int co = ((hk * 4 + quad) ^ s7) << 3;   // stored-chunk short offset
            bf16x8 av[4];
#pragma unroll
            for (int mt = 0; mt < 4; ++mt)
                av[mt] = *(const bf16x8*)&sA[aBase + mt * (16 * BK) + co];
            bf16x8 bv[4];
#pragma unroll
            for (int g = 0; g < 4; ++g)
                bv[g] = *(const bf16x8*)&sB[g * (BH * BK) + bBase + co];
#pragma unroll
            for (int g = 0; g < 4; ++g)
#pragma unroll
                for (int mt = 0; mt < 4; ++mt)
                    acc[g][mt] = __builtin_amdgcn_mfma_f32_16x16x32_bf16(
                        av[mt], bv[g], acc[g][mt], 0, 0, 0);
        }
    }

    // Epilogue: wave-local. C/D: col=lane&15 -> n, row=quad*4+i -> m-within-16.
    {
        int n = nBase + wh * 16 + l16;
        float bi = b_i[n], bf = b_f[n], bo = b_o[n], bc = b_c[n];
#pragma unroll
        for (int mt = 0; mt < 4; ++mt) {
#pragma unroll
            for (int i = 0; i < 4; ++i) {
                int m = mBase + wm * 64 + mt * 16 + quad * 4 + i;
                float zi = acc[0][mt][i] + bi;
                float zf = acc[1][mt][i] + bf;
                float zo = acc[2][mt][i] + bo;
                float zc = acc[3][mt][i] + bc;
                float ig = sigmoid_f(zi);
                float fg = sigmoid_f(zf);
                float og = sigmoid_f(zo);
                float ch = tanh_f(zc);
                size_t idx = (size_t)m * H_DIM + n;
                float c = fg * c_prev[idx] + ig * ch;
                c_out[idx] = c;
                h_out[idx] = og * tanh_f(c);
            }
        }
    }
}

extern "C" void kernel_launch(void* const* d_in, const int* in_sizes, int n_in,
                              void* d_out, int out_size, void* d_ws, size_t ws_size,
                              hipStream_t stream) {
    const float* x_t   = (const float*)d_in[0];
    const float* h_t_1 = (const float*)d_in[1];
    const float* c_t_1 = (const float*)d_in[2];
    const float* W_i   = (const float*)d_in[3];
    const float* b_i   = (const float*)d_in[4];
    const float* W_f   = (const float*)d_in[5];
    const float* b_f   = (const float*)d_in[6];
    const float* W_o   = (const float*)d_in[7];
    const float* b_o   = (const float*)d_in[8];
    const float* W_c   = (const float*)d_in[9];
    const float* b_c   = (const float*)d_in[10];

    float* h_out = (float*)d_out;
    float* c_out = h_out + (size_t)M_DIM * H_DIM;

    dim3 grid(H_DIM / BH, M_DIM / BM);   // (64, 32)

    const size_t need = (size_t)M_DIM * K_DIM * 2 + (size_t)4 * H_DIM * K_DIM * 2; // 96 MB
    if (ws_size >= need) {
        unsigned short* xh_bf = (unsigned short*)d_ws;
        unsigned short* w_bf  = xh_bf + (size_t)M_DIM * K_DIM;
        int total_threads = (M_DIM * K_DIM + 4 * H_DIM * K_DIM) / 8;  // 6,291,456
        convert_all<<<total_threads / 256, 256, 0, stream>>>(
            x_t, h_t_1, W_i, W_f, W_o, W_c, (u16x8*)xh_bf, (u16x8*)w_bf);
        lstm_gemm<true><<<grid, 256, 0, stream>>>(
            xh_bf, w_bf, nullptr, nullptr, nullptr, nullptr, nullptr, nullptr,
            b_i, b_f, b_o, b_c, c_t_1, h_out, c_out);
    } else {
        lstm_gemm<false><<<grid, 256, 0, stream>>>(
            nullptr, nullptr, x_t, h_t_1, W_i, W_f, W_o, W_c,
            b_i, b_f, b_o, b_c, c_t_1, h_out, c_out);
    }
}

// Round 7
// 508.306 us; speedup vs baseline: 1.5930x; 1.0326x over previous
//
#include <hip/hip_runtime.h>
#include <hip/hip_bf16.h>

// LSTM cell: z = [x|h] @ Wstack^T + b ; gates -> c_t, h_t.
// M=4096, K=4096, N=2048 per gate x 4 gates. bf16 MFMA GEMM.
// R2: BK64, 16x16x32, 8-slot XOR swizzle (128B rows) -> 0 conflicts. KEEP.
// R3: 32x32x16 / 128 AGPR = occupancy collapse. REVERTED.
// R4: 2x2 wave partition (64m x 16h x 4g per wave): 311us, MfmaUtil 40.6.
// R5: reg diet -> VGPR 64 (4 waves/SIMD). Occupancy 30->38 but dur FLAT and
//     FETCH doubled -> wave count is not the limiter; L2 thrash visible.
// R6(this): BM=256 / 512-thread blocks (B refetch 32->16, staged bytes/CU
//     16->12MB) + XCD-aware swizzle (each XCD owns 2 m-rows; A-tile reuse
//     becomes XCD-local L2 hits). Wave tile & swizzle unchanged.

#define M_DIM 4096
#define K_DIM 4096
#define H_DIM 2048
#define BM 256
#define BH 32          // h-cols per block (per gate)
#define BK 64
#define NTHREADS 512

typedef __attribute__((ext_vector_type(8))) short bf16x8;
typedef __attribute__((ext_vector_type(8))) unsigned short u16x8;
typedef __attribute__((ext_vector_type(4))) float f32x4;

__device__ __forceinline__ unsigned short f2bf(float f) {
    union { float f; unsigned int u; } v; v.f = f;
    unsigned int u = v.u;
    unsigned int r = u + 0x7FFFu + ((u >> 16) & 1u);   // round-to-nearest-even
    return (unsigned short)(r >> 16);
}

__device__ __forceinline__ float sigmoid_f(float x) {
    return 1.0f / (1.0f + __expf(-x));
}
__device__ __forceinline__ float tanh_f(float x) {
    return 2.0f / (1.0f + __expf(-2.0f * x)) - 1.0f;
}

// [rows][64] shorts: 16B chunk c of row r stored at slot (c ^ (r&7)).
__device__ __forceinline__ int sw64(int row, int koff) {
    int c  = koff >> 3;
    int sc = c ^ (row & 7);
    return row * BK + sc * 8 + (koff & 7);
}

__device__ __forceinline__ void async_load16(const unsigned short* g, unsigned short* l) {
    __builtin_amdgcn_global_load_lds(
        (const __attribute__((address_space(1))) void*)g,
        (__attribute__((address_space(3))) void*)l,
        16, 0, 0);
}

// ---------------- fp32 -> bf16 conversion prepass ----------------
__global__ __launch_bounds__(256) void convert_all(
        const float* __restrict__ x, const float* __restrict__ h,
        const float* __restrict__ Wi, const float* __restrict__ Wf,
        const float* __restrict__ Wo, const float* __restrict__ Wc,
        u16x8* __restrict__ xh_bf, u16x8* __restrict__ w_bf) {
    const int XHT = (M_DIM * K_DIM) / 8;          // 2,097,152
    int t = blockIdx.x * 256 + threadIdx.x;       // 0 .. 6,291,455
    const float* src;
    u16x8* dst;
    if (t < XHT) {
        int e = t * 8;
        int row = e >> 12;
        int col = e & 4095;
        src = (col < 2048) ? &x[(size_t)row * 2048 + col]
                           : &h[(size_t)row * 2048 + (col - 2048)];
        dst = xh_bf + t;
    } else {
        int g2 = t - XHT;                         // 0 .. 4,194,303
        long e = (long)g2 * 8;
        int row = (int)(e >> 12);                 // 0..8191
        int col = (int)(e & 4095);
        int gate = row >> 11;
        const float* Ws = (gate == 0) ? Wi : (gate == 1) ? Wf : (gate == 2) ? Wo : Wc;
        src = &Ws[(size_t)(row & 2047) * 4096 + col];
        dst = w_bf + g2;
    }
    float4 v0 = *(const float4*)src;
    float4 v1 = *(const float4*)(src + 4);
    u16x8 o;
    o[0] = f2bf(v0.x); o[1] = f2bf(v0.y); o[2] = f2bf(v0.z); o[3] = f2bf(v0.w);
    o[4] = f2bf(v1.x); o[5] = f2bf(v1.y); o[6] = f2bf(v1.z); o[7] = f2bf(v1.w);
    *dst = o;
}

// ---------------- fused LSTM GEMM ----------------
// 1D grid of 1024 blocks, XCD-swizzled: xcd = bid&7 owns m-rows {2*xcd, 2*xcd+1}.
// Block: 512 threads = 8 waves in 4m x 2h. Wave: 64m x 16h x 4 gates.
template <bool DMA>
__global__ __launch_bounds__(NTHREADS, 2) void lstm_gemm(
    const unsigned short* __restrict__ xh_bf, const unsigned short* __restrict__ w_bf,
    const float* __restrict__ x_t, const float* __restrict__ h_t_1,
    const float* __restrict__ Wi, const float* __restrict__ Wf,
    const float* __restrict__ Wo, const float* __restrict__ Wc,
    const float* __restrict__ b_i, const float* __restrict__ b_f,
    const float* __restrict__ b_o, const float* __restrict__ b_c,
    const float* __restrict__ c_prev,
    float* __restrict__ h_out, float* __restrict__ c_out) {

    __shared__ __align__(16) unsigned short sA[BM * BK];      // [256][64] 32KB
    __shared__ __align__(16) unsigned short sB[4 * BH * BK];  // [4][32][64] 16KB

    const int tid  = threadIdx.x;
    const int w    = tid >> 6;
    const int lane = tid & 63;
    const int l16  = lane & 15;
    const int quad = lane >> 4;
    const int wm   = w & 3;            // 4 m-groups of 64 rows
    const int wh   = w >> 2;           // 2 h-groups of 16 cols
    const int s7   = l16 & 7;          // swizzle XOR term (all frag rows ==l16 mod 8)

    // XCD-aware block swizzle: same-m-row blocks share an XCD's L2.
    const int bid  = blockIdx.x;       // 0..1023
    const int xcd  = bid & 7;
    const int slot = bid >> 3;         // 0..127
    const int yIdx = xcd * 2 + (slot >> 6);   // 0..15
    const int nIdx = slot & 63;               // 0..63

    const int mBase = yIdx * BM;
    const int nBase = nIdx * BH;

    f32x4 acc[4][4] = {};   // [gate][mt] -- 64 AGPRs

    const int aBase = (wm * 64 + l16) * BK;    // + mt*16*BK (imm) + chunk offset
    const int bBase = (wh * 16 + l16) * BK;    // + g*BH*BK (imm)  + chunk offset

    // DMA source pointers (advance by BK per step).
    const unsigned short* aSrc = nullptr;
    const unsigned short* bSrc = nullptr;
    if constexpr (DMA) {
        int arowi = tid >> 3;                       // 0..63, r adds 64 rows
        int alc   = (tid & 7) ^ (arowi & 7);        // logical chunk for slot tid&7
        aSrc = xh_bf + (size_t)(mBase + arowi) * K_DIM + alc * 8;
        int browi = (tid >> 3) & 31;
        int gate0 = tid >> 8;                       // 0..1, r adds 2 gates
        int blc   = (tid & 7) ^ (browi & 7);
        bSrc = w_bf + (size_t)(gate0 * H_DIM + nBase + browi) * K_DIM + blc * 8;
    }
    const int dmaDst = tid * 8;

    for (int k0 = 0; k0 < K_DIM; k0 += BK) {
        __syncthreads();   // protect LDS while prior step's reads retire
        if constexpr (DMA) {
#pragma unroll
            for (int r = 0; r < 4; ++r)     // A: 256 rows x 8 chunks, 64 rows per r
                async_load16(aSrc + (size_t)r * 64 * K_DIM, &sA[dmaDst + r * 4096]);
#pragma unroll
            for (int r = 0; r < 2; ++r)     // B: gates (gate0 + 2r), 32 rows x 8
                async_load16(bSrc + (size_t)r * 2 * H_DIM * K_DIM, &sB[dmaDst + r * 4096]);
            aSrc += BK;
            bSrc += BK;
        } else {
            const float* Asrc = (k0 < 2048) ? x_t : h_t_1;
            int kloc = k0 & 2047;
#pragma unroll
            for (int r = 0; r < 8; ++r) {   // A: 4096 float4 chunks
                int cc  = r * NTHREADS + tid;
                int row = cc >> 4;
                int ko  = (cc & 15) * 4;
                float4 v = *(const float4*)&Asrc[(size_t)(mBase + row) * 2048 + kloc + ko];
                *(ushort4*)&sA[sw64(row, ko)] =
                    make_ushort4(f2bf(v.x), f2bf(v.y), f2bf(v.z), f2bf(v.w));
            }
            const float* Wg[4] = {Wi, Wf, Wo, Wc};
#pragma unroll
            for (int r = 0; r < 4; ++r) {   // B: 2048 float4 chunks
                int cc   = r * NTHREADS + tid;
                int gate = cc >> 9;
                int row  = (cc >> 4) & 31;
                int ko   = (cc & 15) * 4;
                float4 v = *(const float4*)&Wg[gate][(size_t)(nBase + row) * K_DIM + k0 + ko];
                *(ushort4*)&sB[gate * (BH * BK) + sw64(row, ko)] =
                    make_ushort4(f2bf(v.x), f2bf(v.y), f2bf(v.z), f2bf(v.w));
            }
        }
        __syncthreads();   // drains vmcnt for global_load_lds too

#pragma unroll
        for (int hk = 0; hk < 2; ++hk) {
            const int co = ((hk * 4 + quad) ^ s7) << 3;   // stored-chunk short offset
            bf16x8 av[4];
#pragma unroll
            for (int mt = 0; mt < 4; ++mt)
                av[mt] = *(const bf16x8*)&sA[aBase + mt * (16 * BK) + co];
            bf16x8 bv[4];
#pragma unroll
            for (int g = 0; g < 4; ++g)
                bv[g] = *(const bf16x8*)&sB[g * (BH * BK) + bBase + co];
#pragma unroll
            for (int g = 0; g < 4; ++g)
#pragma unroll
                for (int mt = 0; mt < 4; ++mt)
                    acc[g][mt] = __builtin_amdgcn_mfma_f32_16x16x32_bf16(
                        av[mt], bv[g], acc[g][mt], 0, 0, 0);
        }
    }

    // Epilogue: wave-local. C/D: col=lane&15 -> n, row=quad*4+i -> m-within-16.
    {
        int n = nBase + wh * 16 + l16;
        float bi = b_i[n], bf = b_f[n], bo = b_o[n], bc = b_c[n];
#pragma unroll
        for (int mt = 0; mt < 4; ++mt) {
#pragma unroll
            for (int i = 0; i < 4; ++i) {
                int m = mBase + wm * 64 + mt * 16 + quad * 4 + i;
                float zi = acc[0][mt][i] + bi;
                float zf = acc[1][mt][i] + bf;
                float zo = acc[2][mt][i] + bo;
                float zc = acc[3][mt][i] + bc;
                float ig = sigmoid_f(zi);
                float fg = sigmoid_f(zf);
                float og = sigmoid_f(zo);
                float ch = tanh_f(zc);
                size_t idx = (size_t)m * H_DIM + n;
                float c = fg * c_prev[idx] + ig * ch;
                c_out[idx] = c;
                h_out[idx] = og * tanh_f(c);
            }
        }
    }
}

extern "C" void kernel_launch(void* const* d_in, const int* in_sizes, int n_in,
                              void* d_out, int out_size, void* d_ws, size_t ws_size,
                              hipStream_t stream) {
    const float* x_t   = (const float*)d_in[0];
    const float* h_t_1 = (const float*)d_in[1];
    const float* c_t_1 = (const float*)d_in[2];
    const float* W_i   = (const float*)d_in[3];
    const float* b_i   = (const float*)d_in[4];
    const float* W_f   = (const float*)d_in[5];
    const float* b_f   = (const float*)d_in[6];
    const float* W_o   = (const float*)d_in[7];
    const float* b_o   = (const float*)d_in[8];
    const float* W_c   = (const float*)d_in[9];
    const float* b_c   = (const float*)d_in[10];

    float* h_out = (float*)d_out;
    float* c_out = h_out + (size_t)M_DIM * H_DIM;

    dim3 grid((H_DIM / BH) * (M_DIM / BM));   // 64 * 16 = 1024, XCD-swizzled in-kernel

    const size_t need = (size_t)M_DIM * K_DIM * 2 + (size_t)4 * H_DIM * K_DIM * 2; // 96 MB
    if (ws_size >= need) {
        unsigned short* xh_bf = (unsigned short*)d_ws;
        unsigned short* w_bf  = xh_bf + (size_t)M_DIM * K_DIM;
        int total_threads = (M_DIM * K_DIM + 4 * H_DIM * K_DIM) / 8;  // 6,291,456
        convert_all<<<total_threads / 256, 256, 0, stream>>>(
            x_t, h_t_1, W_i, W_f, W_o, W_c, (u16x8*)xh_bf, (u16x8*)w_bf);
        lstm_gemm<true><<<grid, NTHREADS, 0, stream>>>(
            xh_bf, w_bf, nullptr, nullptr, nullptr, nullptr, nullptr, nullptr,
            b_i, b_f, b_o, b_c, c_t_1, h_out, c_out);
    } else {
        lstm_gemm<false><<<grid, NTHREADS, 0, stream>>>(
            nullptr, nullptr, x_t, h_t_1, W_i, W_f, W_o, W_c,
            b_i, b_f, b_o, b_c, c_t_1, h_out, c_out);
    }
}